// Round 4
// baseline (67.216 us; speedup 1.0000x reference)
//
#include <hip/hip_runtime.h>

#define NQ 8
#define NL 4
#define BATCH 4096

// ---------------------------------------------------------------------------
// Layout: one wave = 1 sample (256 amps). Amp a = (lane << 2) | r, r = 0..3.
// Wire i <-> bit (7 - i) of a (C-order flatten, wire 0 = MSB):
//   wire 0..5 <-> lane bits 5..0   (cross-lane)
//   wire 6,7  <-> reg  bits 1,0    (register ops)
// Cross-lane exchange per wire:
//   wire 0: xor32 -> __shfl_xor      wire 1: xor16 -> ds_swizzle 0x401F
//   wire 2: xor8  -> DPP row_ror:8   wire 3: xor4  -> ds_swizzle 0x101F
//   wire 4: xor2  -> DPP quad_perm   wire 5: xor1  -> DPP quad_perm
// 4096 waves total = 4 waves/SIMD (vs 1 in the previous round).
// ---------------------------------------------------------------------------

template <int CTRL>
__device__ __forceinline__ float dppx(float v) {
  return __int_as_float(
      __builtin_amdgcn_update_dpp(0, __float_as_int(v), CTRL, 0xF, 0xF, true));
}

template <int MASK>   // xor swizzle within 32-lane groups
__device__ __forceinline__ float swzx(float v) {
  return __int_as_float(
      __builtin_amdgcn_ds_swizzle(__float_as_int(v), (MASK << 10) | 0x1F));
}

__device__ __forceinline__ float xor32(float v) { return __shfl_xor(v, 32, 64); }

// exchange along lane-wire W (0..5): partner differs in lane bit (5 - W)
template <int W>
__device__ __forceinline__ float xl(float v) {
  if constexpr (W == 0) return xor32(v);
  else if constexpr (W == 1) return swzx<16>(v);
  else if constexpr (W == 2) return dppx<0x128>(v);   // row_ror:8 == lane^8
  else if constexpr (W == 3) return swzx<4>(v);
  else if constexpr (W == 4) return dppx<0x4E>(v);    // quad_perm [2,3,0,1] == ^2
  else return dppx<0xB1>(v);                          // quad_perm [1,0,3,2] == ^1
}

template <int W>
__device__ __forceinline__ void ry_gate(float re[4], float im[4],
                                        float c, float s, int lane) {
  if constexpr (W <= 5) {
    const float ss = ((lane >> (5 - W)) & 1) ? s : -s;
    float pr[4], pi[4];
#pragma unroll
    for (int r = 0; r < 4; ++r) { pr[r] = xl<W>(re[r]); pi[r] = xl<W>(im[r]); }
#pragma unroll
    for (int r = 0; r < 4; ++r) {
      re[r] = c * re[r] + ss * pr[r];
      im[r] = c * im[r] + ss * pi[r];
    }
  } else {
    constexpr int m = (W == 6) ? 2 : 1;
#pragma unroll
    for (int r = 0; r < 4; ++r) {
      if ((r & m) == 0) {
        const int r1 = r | m;
        float a0r = re[r], a1r = re[r1], a0i = im[r], a1i = im[r1];
        re[r]  = c * a0r - s * a1r;  re[r1] = s * a0r + c * a1r;
        im[r]  = c * a0i - s * a1i;  im[r1] = s * a0i + c * a1i;
      }
    }
  }
}

template <int W>
__device__ __forceinline__ void rz_gate(float re[4], float im[4],
                                        float c, float s, int lane) {
  // amp *= (c - i s) when wire-bit 0, (c + i s) when wire-bit 1
  if constexpr (W <= 5) {
    const float ss = ((lane >> (5 - W)) & 1) ? s : -s;
#pragma unroll
    for (int r = 0; r < 4; ++r) {
      float nr = re[r] * c - im[r] * ss;
      float ni = im[r] * c + re[r] * ss;
      re[r] = nr; im[r] = ni;
    }
  } else {
    constexpr int m = (W == 6) ? 2 : 1;
#pragma unroll
    for (int r = 0; r < 4; ++r) {
      const float ss = (r & m) ? s : -s;   // compile-time sign
      float nr = re[r] * c - im[r] * ss;
      float ni = im[r] * c + re[r] * ss;
      re[r] = nr; im[r] = ni;
    }
  }
}

// CNOT with lane-wire target W: lanes with ctrl bit set take their partner
template <int W>
__device__ __forceinline__ void cnot_lane(float re[4], float im[4], bool p) {
  float pr[4], pi[4];
#pragma unroll
  for (int r = 0; r < 4; ++r) { pr[r] = xl<W>(re[r]); pi[r] = xl<W>(im[r]); }
#pragma unroll
  for (int r = 0; r < 4; ++r) {
    re[r] = p ? pr[r] : re[r];
    im[r] = p ? pi[r] : im[r];
  }
}

__device__ __forceinline__ void cnot_ring(float re[4], float im[4], int lane) {
  cnot_lane<1>(re, im, (lane & 32) != 0);  // CNOT(0,1)
  cnot_lane<2>(re, im, (lane & 16) != 0);  // CNOT(1,2)
  cnot_lane<3>(re, im, (lane & 8) != 0);   // CNOT(2,3)
  cnot_lane<4>(re, im, (lane & 4) != 0);   // CNOT(3,4)
  cnot_lane<5>(re, im, (lane & 2) != 0);   // CNOT(4,5)
  // CNOT(5,6): ctrl lane bit0, tgt reg bit1 — predicated swap r0<->r2, r1<->r3
  {
    const bool p = (lane & 1) != 0;
#pragma unroll
    for (int r = 0; r < 2; ++r) {
      float t0 = re[r], t1 = re[r + 2];
      re[r] = p ? t1 : t0; re[r + 2] = p ? t0 : t1;
      t0 = im[r]; t1 = im[r + 2];
      im[r] = p ? t1 : t0; im[r + 2] = p ? t0 : t1;
    }
  }
  // CNOT(6,7): ctrl reg bit1, tgt reg bit0 — compile-time rename r2<->r3
  { float t = re[2]; re[2] = re[3]; re[3] = t;
    t = im[2]; im[2] = im[3]; im[3] = t; }
  // CNOT(7,0): ctrl reg bit0, tgt lane bit5 — odd regs take xor32 partner
  re[1] = xor32(re[1]); im[1] = xor32(im[1]);
  re[3] = xor32(re[3]); im[3] = xor32(im[3]);
}

__global__ __launch_bounds__(256) void vqc_kernel(const float* __restrict__ x,
                                                  const float* __restrict__ w,
                                                  float* __restrict__ out) {
  const int lane = (int)(threadIdx.x & 63);
  const int s = (int)((blockIdx.x * blockDim.x + threadIdx.x) >> 6);  // sample

  float re[4], im[4];
#pragma unroll
  for (int r = 0; r < 4; ++r) { re[r] = 0.f; im[r] = 0.f; }
  if (lane == 0) re[0] = 1.f;   // |0...0>

  // Angle encoding: RY(x_i) on wire i
  {
    const float4 x0 = *(const float4*)&x[s * 8];
    const float4 x1 = *(const float4*)&x[s * 8 + 4];
    float c, sn;
    __sincosf(x0.x * 0.5f, &sn, &c); ry_gate<0>(re, im, c, sn, lane);
    __sincosf(x0.y * 0.5f, &sn, &c); ry_gate<1>(re, im, c, sn, lane);
    __sincosf(x0.z * 0.5f, &sn, &c); ry_gate<2>(re, im, c, sn, lane);
    __sincosf(x0.w * 0.5f, &sn, &c); ry_gate<3>(re, im, c, sn, lane);
    __sincosf(x1.x * 0.5f, &sn, &c); ry_gate<4>(re, im, c, sn, lane);
    __sincosf(x1.y * 0.5f, &sn, &c); ry_gate<5>(re, im, c, sn, lane);
    __sincosf(x1.z * 0.5f, &sn, &c); ry_gate<6>(re, im, c, sn, lane);
    __sincosf(x1.w * 0.5f, &sn, &c); ry_gate<7>(re, im, c, sn, lane);
  }

#pragma unroll
  for (int l = 0; l < NL; ++l) {
    cnot_ring(re, im, lane);
    const float* wl = &w[l * NQ * 2];
#define APPLY_ROT(W) { float cy, sy, cz, sz;            \
    __sincosf(wl[(W) * 2 + 0] * 0.5f, &sy, &cy);        \
    __sincosf(wl[(W) * 2 + 1] * 0.5f, &sz, &cz);        \
    ry_gate<W>(re, im, cy, sy, lane);                   \
    rz_gate<W>(re, im, cz, sz, lane); }
    APPLY_ROT(0) APPLY_ROT(1) APPLY_ROT(2) APPLY_ROT(3)
    APPLY_ROT(4) APPLY_ROT(5) APPLY_ROT(6) APPLY_ROT(7)
#undef APPLY_ROT
  }

  // <Z_0>: wire 0 = amp bit 7 = lane bit 5
  float acc = 0.f;
#pragma unroll
  for (int r = 0; r < 4; ++r) acc += re[r] * re[r] + im[r] * im[r];
  acc = (lane & 32) ? -acc : acc;
  acc += dppx<0xB1>(acc);    // ^1
  acc += dppx<0x4E>(acc);    // ^2
  acc += swzx<4>(acc);       // ^4
  acc += dppx<0x128>(acc);   // ^8
  acc += swzx<16>(acc);      // ^16
  acc += xor32(acc);         // ^32
  if (lane == 0) out[s] = acc;
}

extern "C" void kernel_launch(void* const* d_in, const int* in_sizes, int n_in,
                              void* d_out, int out_size, void* d_ws, size_t ws_size,
                              hipStream_t stream) {
  const float* x = (const float*)d_in[0];   // (4096, 8) f32
  const float* w = (const float*)d_in[1];   // (4, 8, 2) f32
  float* out = (float*)d_out;               // (4096,) f32
  (void)in_sizes; (void)n_in; (void)out_size; (void)d_ws; (void)ws_size;

  // one wave per sample: 4096 waves = 1024 blocks x 256 threads, 4 waves/SIMD
  dim3 grid(BATCH / 4), block(256);
  hipLaunchKernelGGL(vqc_kernel, grid, block, 0, stream, x, w, out);
}